// Round 3
// baseline (508.268 us; speedup 1.0000x reference)
//
#include <hip/hip_runtime.h>
#include <math.h>

#define FLT_BIG 3.402823466e38f
typedef unsigned int uint;
typedef unsigned short ushort;

__device__ inline float bl(uint u) { return __uint_as_float(u << 16); }
__device__ inline float bh(uint u) { return __uint_as_float(u & 0xffff0000u); }
__device__ inline float bs(ushort u) { return __uint_as_float(((uint)u) << 16); }
__device__ inline ushort f2bf(float f) {  // RNE
    uint u = __float_as_uint(f);
    return (ushort)((u + 0x7fffu + ((u >> 16) & 1u)) >> 16);
}

// ---------------------------------------------------------------- min(xyz)
__global__ void init_min_kernel(float* mn) {
    if (threadIdx.x < 3) mn[threadIdx.x] = FLT_BIG;
}

__global__ void min_reduce_kernel(const float* __restrict__ xyz, int n, float* mn) {
    float m0 = FLT_BIG, m1 = FLT_BIG, m2 = FLT_BIG;
    for (int i = blockIdx.x * blockDim.x + threadIdx.x; i < n; i += gridDim.x * blockDim.x) {
        m0 = fminf(m0, xyz[3 * i + 0]);
        m1 = fminf(m1, xyz[3 * i + 1]);
        m2 = fminf(m2, xyz[3 * i + 2]);
    }
#pragma unroll
    for (int off = 32; off > 0; off >>= 1) {
        m0 = fminf(m0, __shfl_down(m0, off));
        m1 = fminf(m1, __shfl_down(m1, off));
        m2 = fminf(m2, __shfl_down(m2, off));
    }
    if ((threadIdx.x & 63) == 0) {
        // xyz >= 0 so float bits are monotone under signed int compare
        atomicMin((int*)&mn[0], __float_as_int(m0));
        atomicMin((int*)&mn[1], __float_as_int(m1));
        atomicMin((int*)&mn[2], __float_as_int(m2));
    }
}

// ---------------------------------------------------------------- table repack (fp32 -> bf16)
// src layout [idx][h*16+d][c] (stride-3 in d) -> dst [c][idx][h*16+d] contiguous bf16
__global__ void repack_kernel(const float* __restrict__ tq,
                              const float* __restrict__ tk,
                              const float* __restrict__ tv,
                              ushort* __restrict__ rq, ushort* __restrict__ rk,
                              ushort* __restrict__ rv) {
    int i = blockIdx.x * 256 + threadIdx.x;  // over 3*64*96 = 18432
    if (i < 3 * 64 * 96) {
        int c = i / (64 * 96);
        int rem = i - c * 64 * 96;
        int idx = rem / 96;
        int hd = rem - idx * 96;
        int src = (idx * 96 + hd) * 3 + c;
        rq[i] = f2bf(tq[src]);
        rk[i] = f2bf(tk[src]);
        rv[i] = f2bf(tv[src]);
    }
}

// ---------------------------------------------------------------- GEMM (n,96)@(96,96chunk)
// W chunk in LDS (only LDS traffic, minimal-sweep b128 reads); X read directly
// from global (L1-resident per block, lane-broadcast). Thread: 4 cols x 8 rows,
// rows strided by 8 so per-instr row set is 8 distinct lines.
__global__ __launch_bounds__(192) void gemm96_kernel(
    const float* __restrict__ X, const float* __restrict__ W, int wstride,
    const float* __restrict__ bias, float* __restrict__ out0, int st0,
    float* __restrict__ out1, int st1, float* __restrict__ out2, int st2,
    float scale0, int n) {
    __shared__ float Wl[96 * 96];
    const int t = threadIdx.x;
    const int c = blockIdx.x;
    float* outp = (c == 0) ? out0 : (c == 1 ? out1 : out2);
    const int ost = (c == 0) ? st0 : (c == 1 ? st1 : st2);  // in float4 units
    const float scale = (c == 0) ? scale0 : 1.0f;

    for (int idx = t; idx < 9216; idx += 192) {
        int d = idx / 96, o = idx - d * 96;
        Wl[idx] = W[d * wstride + c * 96 + o];
    }

    const int os = t % 24;  // float4 col slot
    const int rg = t / 24;  // 0..7
    const int rbase = blockIdx.y * 64;
    float4 bv = ((const float4*)(bias + c * 96))[os];
    __syncthreads();

    int rowc[8];
#pragma unroll
    for (int r = 0; r < 8; r++) {
        int row = rbase + rg + 8 * r;
        rowc[r] = (row < n) ? row : 0;
    }

    float4 acc[8];
#pragma unroll
    for (int r = 0; r < 8; r++) acc[r] = bv;

    const float4* X4 = (const float4*)X;
    const float4* W4 = (const float4*)Wl;
    for (int d4 = 0; d4 < 24; d4++) {
        float4 xv[8];
#pragma unroll
        for (int r = 0; r < 8; r++) xv[r] = X4[(size_t)rowc[r] * 24 + d4];
        float4 w0 = W4[(d4 * 4 + 0) * 24 + os];
        float4 w1 = W4[(d4 * 4 + 1) * 24 + os];
        float4 w2 = W4[(d4 * 4 + 2) * 24 + os];
        float4 w3 = W4[(d4 * 4 + 3) * 24 + os];
#pragma unroll
        for (int r = 0; r < 8; r++) {
            acc[r].x += xv[r].x * w0.x + xv[r].y * w1.x + xv[r].z * w2.x + xv[r].w * w3.x;
            acc[r].y += xv[r].x * w0.y + xv[r].y * w1.y + xv[r].z * w2.y + xv[r].w * w3.y;
            acc[r].z += xv[r].x * w0.z + xv[r].y * w1.z + xv[r].z * w2.z + xv[r].w * w3.z;
            acc[r].w += xv[r].x * w0.w + xv[r].y * w1.w + xv[r].z * w2.w + xv[r].w * w3.w;
        }
    }

    float4* O4 = (float4*)outp;
#pragma unroll
    for (int r = 0; r < 8; r++) {
        int row = rbase + rg + 8 * r;
        if (row < n) {
            float4 v = acc[r];
            v.x *= scale; v.y *= scale; v.z *= scale; v.w *= scale;
            O4[(size_t)row * ost + os] = v;
        }
    }
}

// ---------------------------------------------------------------- fused attention
// kv rows are interleaved (k[96] || v[96], 768B contiguous per edge) so each
// edge gather is one burst. float4 gather, 8 slots/thread. Tables in bf16.
__global__ __launch_bounds__(192) void attn_kernel(
    const float* q, const float* __restrict__ kv, const float* __restrict__ xyz,
    const int* __restrict__ index_1, const ushort* __restrict__ rq,
    const ushort* __restrict__ rk, const ushort* __restrict__ rv,
    const float* __restrict__ mn, const float* __restrict__ shiftp, float* xout,
    int n) {
    __shared__ float qs[2][96];
    __shared__ float kvs[2][16][204];  // pitch 204 floats (51 granules, odd)
    __shared__ float smw[2][6][16];
    __shared__ int ridx[2][16][3];

    const int s = threadIdx.x / 96;
    const int tp = threadIdx.x - s * 96;
    const int p = blockIdx.x * 2 + s;
    const bool active = p < n;
    const float shift = shiftp[0];

    // ---- gather: 16 edges x 192 floats = 768 float4 slots; thread slot = tp + 96w
    const int c4 = tp % 48;   // float4 slot within kv row
    const int e0 = tp / 48;   // 0..1
    float4 kvreg[8];
    if (active) {
        int jds[8];
#pragma unroll
        for (int w = 0; w < 8; w++) jds[w] = index_1[(size_t)p * 16 + e0 + 2 * w];
        const float4* KV4 = (const float4*)kv;
#pragma unroll
        for (int w = 0; w < 8; w++) kvreg[w] = KV4[(size_t)jds[w] * 48 + c4];
        qs[s][tp] = q[(size_t)p * 96 + tp];
    }

    // ---- rel quantized index: 48 threads/point, one per (e,c)
    if (active && tp < 48) {
        const int e = tp & 15;
        const int c = tp >> 4;
        const int jdx = index_1[(size_t)p * 16 + e];
        const float mnc = mn[c];
        float xi = floorf(fmodf(xyz[3 * p + c] - mnc + shift, 4.0f) * 4.0f);
        float xj = floorf(fmodf(xyz[3 * jdx + c] - mnc + shift, 4.0f) * 4.0f);
        ridx[s][e][c] = (int)(xi - xj) + 15;
    }

    if (active) {
#pragma unroll
        for (int w = 0; w < 8; w++)
            *(float4*)&kvs[s][e0 + 2 * w][c4 * 4] = kvreg[w];
    }
    __syncthreads();

    // ---- scores + shuffle softmax: thread (h,e)
    const int h = tp >> 4;
    {
        const int e = tp & 15;
        const float4* q4 = (const float4*)&qs[s][h * 16];
        const float4* k4 = (const float4*)&kvs[s][e][h * 16];
        float4 qa = q4[0], qb = q4[1], qc = q4[2], qd = q4[3];
        float4 ka = k4[0], kb = k4[1], kc = k4[2], kd = k4[3];
        float a = qa.x * ka.x + qa.y * ka.y + qa.z * ka.z + qa.w * ka.w +
                  qb.x * kb.x + qb.y * kb.y + qb.z * kb.z + qb.w * kb.w +
                  qc.x * kc.x + qc.y * kc.y + qc.z * kc.z + qc.w * kc.w +
                  qd.x * kd.x + qd.y * kd.y + qd.z * kd.z + qd.w * kd.w;
#pragma unroll
        for (int c = 0; c < 3; c++) {
            int idx = ridx[s][e][c];
            const uint4* tq4 = (const uint4*)(rq + (c * 64 + idx) * 96 + h * 16);
            const uint4* tk4 = (const uint4*)(rk + (c * 64 + idx) * 96 + h * 16);
            uint4 t0 = tq4[0], t1 = tq4[1];
            a += qa.x * bl(t0.x) + qa.y * bh(t0.x) + qa.z * bl(t0.y) + qa.w * bh(t0.y) +
                 qb.x * bl(t0.z) + qb.y * bh(t0.z) + qb.z * bl(t0.w) + qb.w * bh(t0.w) +
                 qc.x * bl(t1.x) + qc.y * bh(t1.x) + qc.z * bl(t1.y) + qc.w * bh(t1.y) +
                 qd.x * bl(t1.z) + qd.y * bh(t1.z) + qd.z * bl(t1.w) + qd.w * bh(t1.w);
            uint4 u0 = tk4[0], u1 = tk4[1];
            a += ka.x * bl(u0.x) + ka.y * bh(u0.x) + ka.z * bl(u0.y) + ka.w * bh(u0.y) +
                 kb.x * bl(u0.z) + kb.y * bh(u0.z) + kb.z * bl(u0.w) + kb.w * bh(u0.w) +
                 kc.x * bl(u1.x) + kc.y * bh(u1.x) + kc.z * bl(u1.y) + kc.w * bh(u1.y) +
                 kd.x * bl(u1.z) + kd.y * bh(u1.z) + kd.z * bl(u1.w) + kd.w * bh(u1.w);
        }
        // width-16 softmax across e lanes (16-groups stay (s,h)-aligned)
        float m = a;
#pragma unroll
        for (int off = 8; off >= 1; off >>= 1) m = fmaxf(m, __shfl_xor(m, off, 16));
        float ex = __expf(a - m);
        float sum = ex;
#pragma unroll
        for (int off = 8; off >= 1; off >>= 1) sum += __shfl_xor(sum, off, 16);
        if (active) smw[s][h][e] = ex / sum;
    }
    __syncthreads();

    // ---- output: thread owns (h,d)=tp; v part of kv row is floats 96..191
    {
        float x = 0.f;
#pragma unroll
        for (int e = 0; e < 16; e++) {
            float wgt = smw[s][h][e];
            int i0 = ridx[s][e][0], i1 = ridx[s][e][1], i2 = ridx[s][e][2];
            float add = bs(rv[i0 * 96 + tp]) + bs(rv[(64 + i1) * 96 + tp]) +
                        bs(rv[(128 + i2) * 96 + tp]);
            x += wgt * (kvs[s][e][96 + tp] + add);
        }
        if (active) xout[(size_t)p * 96 + tp] = x;  // xout aliases q: own row only
    }
}

// ---------------------------------------------------------------- launch
extern "C" void kernel_launch(void* const* d_in, const int* in_sizes, int n_in,
                              void* d_out, int out_size, void* d_ws, size_t ws_size,
                              hipStream_t stream) {
    const float* feats   = (const float*)d_in[0];
    const float* xyz     = (const float*)d_in[1];
    const int*   index_1 = (const int*)d_in[5];
    const float* shiftp  = (const float*)d_in[6];
    const float* W_qkv   = (const float*)d_in[7];
    const float* b_qkv   = (const float*)d_in[8];
    const float* table_q = (const float*)d_in[9];
    const float* table_k = (const float*)d_in[10];
    const float* table_v = (const float*)d_in[11];
    const float* W_proj  = (const float*)d_in[12];
    const float* b_proj  = (const float*)d_in[13];
    float* out = (float*)d_out;

    const int n = in_sizes[0] / 96;  // 50000

    float* w = (float*)d_ws;
    float* mn    = w;                        // 3 (pad 16)
    float* qbuf  = w + 16;                   // n*96
    float* kvbuf = qbuf + (size_t)n * 96;    // n*192 (k||v interleaved)
    ushort* rq = (ushort*)(kvbuf + (size_t)n * 192);  // 18432 bf16 each
    ushort* rk = rq + 18432;
    ushort* rv = rk + 18432;
    float* xbuf = qbuf;  // alias: q rows consumed only by their own block

    const int GY = (n + 63) / 64;

    init_min_kernel<<<1, 64, 0, stream>>>(mn);
    min_reduce_kernel<<<256, 256, 0, stream>>>(xyz, n, mn);
    repack_kernel<<<(18432 + 255) / 256, 256, 0, stream>>>(table_q, table_k, table_v,
                                                           rq, rk, rv);
    // q -> qbuf (stride 24 float4), k -> kvbuf[:, :96], v -> kvbuf[:, 96:]
    gemm96_kernel<<<dim3(3, GY), 192, 0, stream>>>(feats, W_qkv, 288, b_qkv,
                                                   qbuf, 24, kvbuf, 48, kvbuf + 96, 48,
                                                   0.25f, n);
    attn_kernel<<<(n + 1) / 2, 192, 0, stream>>>(qbuf, kvbuf, xyz, index_1, rq, rk,
                                                 rv, mn, shiftp, xbuf, n);
    gemm96_kernel<<<dim3(1, GY), 192, 0, stream>>>(xbuf, W_proj, 96, b_proj,
                                                   out, 24, out, 24, out, 24, 1.0f, n);
}

// Round 4
// 379.033 us; speedup vs baseline: 1.3410x; 1.3410x over previous
//
#include <hip/hip_runtime.h>
#include <math.h>

#define FLT_BIG 3.402823466e38f
typedef unsigned int uint;
typedef unsigned short ushort;

__device__ inline float bl(uint u) { return __uint_as_float(u << 16); }
__device__ inline float bh(uint u) { return __uint_as_float(u & 0xffff0000u); }
__device__ inline float bs(ushort u) { return __uint_as_float(((uint)u) << 16); }
__device__ inline ushort f2bf(float f) {  // RNE
    uint u = __float_as_uint(f);
    return (ushort)((u + 0x7fffu + ((u >> 16) & 1u)) >> 16);
}
__device__ inline float dot4(float4 a, float4 b) {
    return a.x * b.x + a.y * b.y + a.z * b.z + a.w * b.w;
}

// ---------------------------------------------------------------- min(xyz)
__global__ void min_reduce_kernel(const float* __restrict__ xyz, int n, float* mn) {
    float m0 = FLT_BIG, m1 = FLT_BIG, m2 = FLT_BIG;
    for (int i = blockIdx.x * blockDim.x + threadIdx.x; i < n; i += gridDim.x * blockDim.x) {
        m0 = fminf(m0, xyz[3 * i + 0]);
        m1 = fminf(m1, xyz[3 * i + 1]);
        m2 = fminf(m2, xyz[3 * i + 2]);
    }
#pragma unroll
    for (int off = 32; off > 0; off >>= 1) {
        m0 = fminf(m0, __shfl_down(m0, off));
        m1 = fminf(m1, __shfl_down(m1, off));
        m2 = fminf(m2, __shfl_down(m2, off));
    }
    if ((threadIdx.x & 63) == 0) {
        // xyz >= 0 so float bits are monotone under signed int compare
        atomicMin((int*)&mn[0], __float_as_int(m0));
        atomicMin((int*)&mn[1], __float_as_int(m1));
        atomicMin((int*)&mn[2], __float_as_int(m2));
    }
}

// ---------------------------------------------------------------- table repack (fp32 -> bf16)
// src layout [idx][h*16+d][c] (stride-3 in d) -> dst [c][idx][h*16+d] bf16.
// Also initializes mn (runs before min_reduce on the same stream).
__global__ void repack_kernel(const float* __restrict__ tq,
                              const float* __restrict__ tk,
                              const float* __restrict__ tv,
                              ushort* __restrict__ rq, ushort* __restrict__ rk,
                              ushort* __restrict__ rv, float* mn) {
    if (blockIdx.x == 0 && threadIdx.x < 3) mn[threadIdx.x] = FLT_BIG;
    int i = blockIdx.x * 256 + threadIdx.x;  // over 3*64*96 = 18432
    if (i < 3 * 64 * 96) {
        int c = i / (64 * 96);
        int rem = i - c * 64 * 96;
        int idx = rem / 96;
        int hd = rem - idx * 96;
        int src = (idx * 96 + hd) * 3 + c;
        rq[i] = f2bf(tq[src]);
        rk[i] = f2bf(tk[src]);
        rv[i] = f2bf(tv[src]);
    }
}

// ---------------------------------------------------------------- GEMM (n,96)@(96,96chunk)
// W chunk in LDS; X read directly from global (L1-resident per block).
__global__ __launch_bounds__(192) void gemm96_kernel(
    const float* __restrict__ X, const float* __restrict__ W, int wstride,
    const float* __restrict__ bias, float* __restrict__ out0, int st0,
    float* __restrict__ out1, int st1, float* __restrict__ out2, int st2,
    float scale0, int n) {
    __shared__ float Wl[96 * 96];
    const int t = threadIdx.x;
    const int c = blockIdx.x;
    float* outp = (c == 0) ? out0 : (c == 1 ? out1 : out2);
    const int ost = (c == 0) ? st0 : (c == 1 ? st1 : st2);  // in float4 units
    const float scale = (c == 0) ? scale0 : 1.0f;

    for (int idx = t; idx < 9216; idx += 192) {
        int d = idx / 96, o = idx - d * 96;
        Wl[idx] = W[d * wstride + c * 96 + o];
    }

    const int os = t % 24;  // float4 col slot
    const int rg = t / 24;  // 0..7
    const int rbase = blockIdx.y * 64;
    float4 bv = ((const float4*)(bias + c * 96))[os];
    __syncthreads();

    int rowc[8];
#pragma unroll
    for (int r = 0; r < 8; r++) {
        int row = rbase + rg + 8 * r;
        rowc[r] = (row < n) ? row : 0;
    }

    float4 acc[8];
#pragma unroll
    for (int r = 0; r < 8; r++) acc[r] = bv;

    const float4* X4 = (const float4*)X;
    const float4* W4 = (const float4*)Wl;
    for (int d4 = 0; d4 < 24; d4++) {
        float4 xv[8];
#pragma unroll
        for (int r = 0; r < 8; r++) xv[r] = X4[(size_t)rowc[r] * 24 + d4];
        float4 w0 = W4[(d4 * 4 + 0) * 24 + os];
        float4 w1 = W4[(d4 * 4 + 1) * 24 + os];
        float4 w2 = W4[(d4 * 4 + 2) * 24 + os];
        float4 w3 = W4[(d4 * 4 + 3) * 24 + os];
#pragma unroll
        for (int r = 0; r < 8; r++) {
            acc[r].x += xv[r].x * w0.x + xv[r].y * w1.x + xv[r].z * w2.x + xv[r].w * w3.x;
            acc[r].y += xv[r].x * w0.y + xv[r].y * w1.y + xv[r].z * w2.y + xv[r].w * w3.y;
            acc[r].z += xv[r].x * w0.z + xv[r].y * w1.z + xv[r].z * w2.z + xv[r].w * w3.z;
            acc[r].w += xv[r].x * w0.w + xv[r].y * w1.w + xv[r].z * w2.w + xv[r].w * w3.w;
        }
    }

    float4* O4 = (float4*)outp;
#pragma unroll
    for (int r = 0; r < 8; r++) {
        int row = rbase + rg + 8 * r;
        if (row < n) {
            float4 v = acc[r];
            v.x *= scale; v.y *= scale; v.z *= scale; v.w *= scale;
            O4[(size_t)row * ost + ost == 0 ? 0 : (size_t)row * ost + os] = v;  // placeholder removed below
        }
    }
}

// NOTE: the line above would be a bug; real store loop is in gemm96b below.
// (gemm96_kernel is not used — see gemm96b_kernel)

__global__ __launch_bounds__(192) void gemm96b_kernel(
    const float* __restrict__ X, const float* __restrict__ W, int wstride,
    const float* __restrict__ bias, float* __restrict__ out0, int st0,
    float* __restrict__ out1, int st1, float* __restrict__ out2, int st2,
    float scale0, int n) {
    __shared__ float Wl[96 * 96];
    const int t = threadIdx.x;
    const int c = blockIdx.x;
    float* outp = (c == 0) ? out0 : (c == 1 ? out1 : out2);
    const int ost = (c == 0) ? st0 : (c == 1 ? st1 : st2);  // in float4 units
    const float scale = (c == 0) ? scale0 : 1.0f;

    for (int idx = t; idx < 9216; idx += 192) {
        int d = idx / 96, o = idx - d * 96;
        Wl[idx] = W[d * wstride + c * 96 + o];
    }

    const int os = t % 24;  // float4 col slot
    const int rg = t / 24;  // 0..7
    const int rbase = blockIdx.y * 64;
    float4 bv = ((const float4*)(bias + c * 96))[os];
    __syncthreads();

    int rowc[8];
#pragma unroll
    for (int r = 0; r < 8; r++) {
        int row = rbase + rg + 8 * r;
        rowc[r] = (row < n) ? row : 0;
    }

    float4 acc[8];
#pragma unroll
    for (int r = 0; r < 8; r++) acc[r] = bv;

    const float4* X4 = (const float4*)X;
    const float4* W4 = (const float4*)Wl;
    for (int d4 = 0; d4 < 24; d4++) {
        float4 xv[8];
#pragma unroll
        for (int r = 0; r < 8; r++) xv[r] = X4[(size_t)rowc[r] * 24 + d4];
        float4 w0 = W4[(d4 * 4 + 0) * 24 + os];
        float4 w1 = W4[(d4 * 4 + 1) * 24 + os];
        float4 w2 = W4[(d4 * 4 + 2) * 24 + os];
        float4 w3 = W4[(d4 * 4 + 3) * 24 + os];
#pragma unroll
        for (int r = 0; r < 8; r++) {
            acc[r].x += xv[r].x * w0.x + xv[r].y * w1.x + xv[r].z * w2.x + xv[r].w * w3.x;
            acc[r].y += xv[r].x * w0.y + xv[r].y * w1.y + xv[r].z * w2.y + xv[r].w * w3.y;
            acc[r].z += xv[r].x * w0.z + xv[r].y * w1.z + xv[r].z * w2.z + xv[r].w * w3.z;
            acc[r].w += xv[r].x * w0.w + xv[r].y * w1.w + xv[r].z * w2.w + xv[r].w * w3.w;
        }
    }

    float4* O4 = (float4*)outp;
#pragma unroll
    for (int r = 0; r < 8; r++) {
        int row = rbase + rg + 8 * r;
        if (row < n) {
            float4 v = acc[r];
            v.x *= scale; v.y *= scale; v.z *= scale; v.w *= scale;
            O4[(size_t)row * ost + os] = v;
        }
    }
}

// ---------------------------------------------------------------- fused attention
// Thread (h,e) per point: gathers its k fragment straight into registers (no
// LDS round-trip, no staging array -> no spill), v fragment -> small LDS tile.
__global__ __launch_bounds__(192) void attn_kernel(
    const float* q, const float* __restrict__ kv, const float* __restrict__ xyz,
    const int* __restrict__ index_1, const ushort* __restrict__ rq,
    const ushort* __restrict__ rk, const ushort* __restrict__ rv,
    const float* __restrict__ mn, const float* __restrict__ shiftp, float* xout,
    int n) {
    __shared__ float qs[2][96];
    __shared__ float vs[2][16][100];  // v rows, pitch 100 floats
    __shared__ float smw[2][6][16];
    __shared__ int ridx[2][16][3];

    const int s = threadIdx.x / 96;
    const int tp = threadIdx.x - s * 96;
    const int p = blockIdx.x * 2 + s;
    const bool active = p < n;
    const float shift = shiftp[0];

    const int h = tp >> 4;  // 0..5
    const int e = tp & 15;

    int jd = 0;
    if (active) jd = index_1[(size_t)p * 16 + e];

    // ---- rel quantized index: 48 threads/point, one per (e,c)
    if (active && tp < 48) {
        const int c = tp >> 4;
        const float mnc = mn[c];
        float xi = floorf(fmodf(xyz[3 * p + c] - mnc + shift, 4.0f) * 4.0f);
        float xj = floorf(fmodf(xyz[3 * jd + c] - mnc + shift, 4.0f) * 4.0f);
        ridx[s][e][c] = (int)(xi - xj) + 15;
    }

    // ---- gather: k fragment into regs, v fragment into LDS, q row into LDS
    float4 k0, k1, k2, k3;
    k0 = k1 = k2 = k3 = make_float4(0.f, 0.f, 0.f, 0.f);
    if (active) {
        qs[s][tp] = q[(size_t)p * 96 + tp];
        const float4* row = (const float4*)kv + (size_t)jd * 48;
        k0 = row[h * 4 + 0];
        k1 = row[h * 4 + 1];
        k2 = row[h * 4 + 2];
        k3 = row[h * 4 + 3];
        float4 v0 = row[24 + h * 4 + 0];
        float4 v1 = row[24 + h * 4 + 1];
        float4 v2 = row[24 + h * 4 + 2];
        float4 v3 = row[24 + h * 4 + 3];
        *(float4*)&vs[s][e][h * 16 + 0]  = v0;
        *(float4*)&vs[s][e][h * 16 + 4]  = v1;
        *(float4*)&vs[s][e][h * 16 + 8]  = v2;
        *(float4*)&vs[s][e][h * 16 + 12] = v3;
    }
    __syncthreads();

    // ---- score: qk + bias, then width-16 shuffle softmax
    {
        const float4* q4 = (const float4*)&qs[s][h * 16];
        float4 qa = q4[0], qb = q4[1], qc = q4[2], qd = q4[3];
        float a = dot4(qa, k0) + dot4(qb, k1) + dot4(qc, k2) + dot4(qd, k3);
#pragma unroll
        for (int c = 0; c < 3; c++) {
            int idx = ridx[s][e][c];
            const uint4* tq4 = (const uint4*)(rq + (c * 64 + idx) * 96 + h * 16);
            const uint4* tk4 = (const uint4*)(rk + (c * 64 + idx) * 96 + h * 16);
            uint4 t0 = tq4[0], t1 = tq4[1];
            a += qa.x * bl(t0.x) + qa.y * bh(t0.x) + qa.z * bl(t0.y) + qa.w * bh(t0.y) +
                 qb.x * bl(t0.z) + qb.y * bh(t0.z) + qb.z * bl(t0.w) + qb.w * bh(t0.w) +
                 qc.x * bl(t1.x) + qc.y * bh(t1.x) + qc.z * bl(t1.y) + qc.w * bh(t1.y) +
                 qd.x * bl(t1.z) + qd.y * bh(t1.z) + qd.z * bl(t1.w) + qd.w * bh(t1.w);
            uint4 u0 = tk4[0], u1 = tk4[1];
            a += k0.x * bl(u0.x) + k0.y * bh(u0.x) + k0.z * bl(u0.y) + k0.w * bh(u0.y) +
                 k1.x * bl(u0.z) + k1.y * bh(u0.z) + k1.z * bl(u0.w) + k1.w * bh(u0.w) +
                 k2.x * bl(u1.x) + k2.y * bh(u1.x) + k2.z * bl(u1.y) + k2.w * bh(u1.y) +
                 k3.x * bl(u1.z) + k3.y * bh(u1.z) + k3.z * bl(u1.w) + k3.w * bh(u1.w);
        }
        // width-16 softmax across e lanes (16-groups stay aligned: 96 ≡ 32 mod 64)
        float m = a;
#pragma unroll
        for (int off = 8; off >= 1; off >>= 1) m = fmaxf(m, __shfl_xor(m, off, 16));
        float ex = __expf(a - m);
        float sum = ex;
#pragma unroll
        for (int off = 8; off >= 1; off >>= 1) sum += __shfl_xor(sum, off, 16);
        if (active) smw[s][h][e] = ex / sum;
    }
    __syncthreads();

    // ---- output: thread owns (h,d)=tp
    {
        float x = 0.f;
#pragma unroll
        for (int ee = 0; ee < 16; ee++) {
            float wgt = smw[s][h][ee];
            int i0 = ridx[s][ee][0], i1 = ridx[s][ee][1], i2 = ridx[s][ee][2];
            float add = bs(rv[i0 * 96 + tp]) + bs(rv[(64 + i1) * 96 + tp]) +
                        bs(rv[(128 + i2) * 96 + tp]);
            x += wgt * (vs[s][ee][tp] + add);
        }
        if (active) xout[(size_t)p * 96 + tp] = x;  // xout aliases q: own row only
    }
}

// ---------------------------------------------------------------- launch
extern "C" void kernel_launch(void* const* d_in, const int* in_sizes, int n_in,
                              void* d_out, int out_size, void* d_ws, size_t ws_size,
                              hipStream_t stream) {
    const float* feats   = (const float*)d_in[0];
    const float* xyz     = (const float*)d_in[1];
    const int*   index_1 = (const int*)d_in[5];
    const float* shiftp  = (const float*)d_in[6];
    const float* W_qkv   = (const float*)d_in[7];
    const float* b_qkv   = (const float*)d_in[8];
    const float* table_q = (const float*)d_in[9];
    const float* table_k = (const float*)d_in[10];
    const float* table_v = (const float*)d_in[11];
    const float* W_proj  = (const float*)d_in[12];
    const float* b_proj  = (const float*)d_in[13];
    float* out = (float*)d_out;

    const int n = in_sizes[0] / 96;  // 50000

    float* w = (float*)d_ws;
    float* mn    = w;                        // 3 (pad 16)
    float* qbuf  = w + 16;                   // n*96
    float* kvbuf = qbuf + (size_t)n * 96;    // n*192 (k||v interleaved)
    ushort* rq = (ushort*)(kvbuf + (size_t)n * 192);  // 18432 bf16 each
    ushort* rk = rq + 18432;
    ushort* rv = rk + 18432;
    float* xbuf = qbuf;  // alias: q rows consumed only by their own block

    const int GY = (n + 63) / 64;

    repack_kernel<<<(18432 + 255) / 256, 256, 0, stream>>>(table_q, table_k, table_v,
                                                           rq, rk, rv, mn);
    min_reduce_kernel<<<256, 256, 0, stream>>>(xyz, n, mn);
    // q -> qbuf (stride 24 float4), k -> kvbuf[:, :96], v -> kvbuf[:, 96:]
    gemm96b_kernel<<<dim3(3, GY), 192, 0, stream>>>(feats, W_qkv, 288, b_qkv,
                                                    qbuf, 24, kvbuf, 48, kvbuf + 96, 48,
                                                    0.25f, n);
    attn_kernel<<<(n + 1) / 2, 192, 0, stream>>>(qbuf, kvbuf, xyz, index_1, rq, rk,
                                                 rv, mn, shiftp, xbuf, n);
    gemm96b_kernel<<<dim3(1, GY), 192, 0, stream>>>(xbuf, W_proj, 96, b_proj,
                                                    out, 24, out, 24, out, 24, 1.0f, n);
}

// Round 5
// 297.846 us; speedup vs baseline: 1.7065x; 1.2726x over previous
//
#include <hip/hip_runtime.h>
#include <math.h>

#define FLT_BIG 3.402823466e38f
typedef unsigned int uint;
typedef unsigned short ushort;
typedef __attribute__((ext_vector_type(8))) short short8;   // 8 bf16 (4 VGPRs)
typedef __attribute__((ext_vector_type(4))) float floatx4;  // MFMA C/D frag

__device__ inline float bl(uint u) { return __uint_as_float(u << 16); }
__device__ inline float bh(uint u) { return __uint_as_float(u & 0xffff0000u); }
__device__ inline float bs(ushort u) { return __uint_as_float(((uint)u) << 16); }
__device__ inline ushort f2bf(float f) {  // RNE
    uint u = __float_as_uint(f);
    return (ushort)((u + 0x7fffu + ((u >> 16) & 1u)) >> 16);
}
__device__ inline float dot4(float4 a, float4 b) {
    return a.x * b.x + a.y * b.y + a.z * b.z + a.w * b.w;
}

// ---------------------------------------------------------------- min(xyz)
__global__ void min_reduce_kernel(const float* __restrict__ xyz, int n, float* mn) {
    float m0 = FLT_BIG, m1 = FLT_BIG, m2 = FLT_BIG;
    for (int i = blockIdx.x * blockDim.x + threadIdx.x; i < n; i += gridDim.x * blockDim.x) {
        m0 = fminf(m0, xyz[3 * i + 0]);
        m1 = fminf(m1, xyz[3 * i + 1]);
        m2 = fminf(m2, xyz[3 * i + 2]);
    }
#pragma unroll
    for (int off = 32; off > 0; off >>= 1) {
        m0 = fminf(m0, __shfl_down(m0, off));
        m1 = fminf(m1, __shfl_down(m1, off));
        m2 = fminf(m2, __shfl_down(m2, off));
    }
    if ((threadIdx.x & 63) == 0) {
        // xyz >= 0 so float bits are monotone under signed int compare
        atomicMin((int*)&mn[0], __float_as_int(m0));
        atomicMin((int*)&mn[1], __float_as_int(m1));
        atomicMin((int*)&mn[2], __float_as_int(m2));
    }
}

// ---------------------------------------------------------------- prep
// mn init; tables [idx][hd][c] -> [c][idx][hd] bf16; W_qkv/W_proj -> bf16
// transposed WT[outcol][k]; feats -> bf16 row-major.
__global__ void prep_kernel(const float* __restrict__ feats,
                            const float* __restrict__ W_qkv,
                            const float* __restrict__ W_proj,
                            const float* __restrict__ tq, const float* __restrict__ tk,
                            const float* __restrict__ tv, ushort* __restrict__ feats_bf,
                            ushort* __restrict__ wtqkv, ushort* __restrict__ wtproj,
                            ushort* __restrict__ rq, ushort* __restrict__ rk,
                            ushort* __restrict__ rv, float* mn, int n) {
    int tid = blockIdx.x * 256 + threadIdx.x;
    if (tid < 3) mn[tid] = FLT_BIG;
    if (tid < 18432) {  // tables: 3*64*96
        int c = tid / 6144, rem = tid - c * 6144;
        int idx = rem / 96, hd = rem - idx * 96;
        int src = (idx * 96 + hd) * 3 + c;
        rq[tid] = f2bf(tq[src]);
        rk[tid] = f2bf(tk[src]);
        rv[tid] = f2bf(tv[src]);
    }
    if (tid < 27648) {  // WT_qkv[j][d] = W_qkv[d][j], j over 288
        int j = tid / 96, d = tid - j * 96;
        wtqkv[tid] = f2bf(W_qkv[d * 288 + j]);
    }
    if (tid < 9216) {  // WT_proj[j][d] = W_proj[d][j]
        int j = tid / 96, d = tid - j * 96;
        wtproj[tid] = f2bf(W_proj[d * 96 + j]);
    }
    int nf4 = n * 24;
    for (int i = tid; i < nf4; i += gridDim.x * 256) {
        float4 f = ((const float4*)feats)[i];
        ushort4 u4;
        u4.x = f2bf(f.x); u4.y = f2bf(f.y); u4.z = f2bf(f.z); u4.w = f2bf(f.w);
        ((ushort4*)feats_bf)[i] = u4;
    }
}

// ---------------------------------------------------------------- MFMA GEMM
// A (n x 96 bf16) @ WT^T (96 x 96 per chunk) + bias. Wave-job: 16 rows x 96
// cols, K=96 (3 mfma k-steps x 6 col-tiles), all operands straight from
// global (WT is L1-resident). ch0 -> fp32 out (stride 96, x scale0);
// ch1/ch2 -> bf16 kv rows (stride 192, v at +96).
// Verified layouts (m89/m91/m120): A[m=lane&15][k=quad*8+j],
// B[k=quad*8+j][nc=lane&15], D[row=quad*4+reg][col=lane&15].
__global__ __launch_bounds__(256) void mfma_gemm_kernel(
    const ushort* __restrict__ A, const ushort* __restrict__ WT,
    const float* __restrict__ bias, float* __restrict__ fout,
    ushort* __restrict__ kvout, float scale0, int n) {
    const int wave = threadIdx.x >> 6;
    const int lane = threadIdx.x & 63;
    const int ch = blockIdx.y;
    const int row0 = (blockIdx.x * 4 + wave) * 16;
    if (row0 >= n) return;
    const int m = lane & 15;
    const int q = lane >> 4;

    const ushort* arow = A + (size_t)(row0 + m) * 96 + q * 8;
    const ushort* wrow = WT + ((size_t)ch * 96 + m) * 96 + q * 8;

    floatx4 acc[6];
#pragma unroll
    for (int ct = 0; ct < 6; ct++) acc[ct] = (floatx4){0.f, 0.f, 0.f, 0.f};

#pragma unroll
    for (int kk = 0; kk < 96; kk += 32) {
        short8 a = *(const short8*)(arow + kk);
#pragma unroll
        for (int ct = 0; ct < 6; ct++) {
            short8 b = *(const short8*)(wrow + ct * 16 * 96 + kk);
            acc[ct] = __builtin_amdgcn_mfma_f32_16x16x32_bf16(a, b, acc[ct], 0, 0, 0);
        }
    }

#pragma unroll
    for (int ct = 0; ct < 6; ct++) {
        int col = ct * 16 + m;
        float bv = bias[ch * 96 + col];
#pragma unroll
        for (int r = 0; r < 4; r++) {
            int row = row0 + q * 4 + r;
            float val = acc[ct][r] + bv;
            if (ch == 0) {
                fout[(size_t)row * 96 + col] = val * scale0;
            } else {
                int off = (ch == 1) ? 0 : 96;
                kvout[(size_t)row * 192 + off + col] = f2bf(val);
            }
        }
    }
}

// ---------------------------------------------------------------- fused attention
// kv rows bf16 (k[96]||v[96], 384B). Thread (h,e): k fragment straight into
// registers (no spill), v fragment expanded into small LDS tile. x out bf16.
__global__ __launch_bounds__(192) void attn_kernel(
    const float* q, const ushort* __restrict__ kv, const float* __restrict__ xyz,
    const int* __restrict__ index_1, const ushort* __restrict__ rq,
    const ushort* __restrict__ rk, const ushort* __restrict__ rv,
    const float* __restrict__ mn, const float* __restrict__ shiftp,
    ushort* xout, int n) {
    __shared__ float qs[2][96];
    __shared__ float vs[2][16][100];  // v rows, pitch 100 floats
    __shared__ float smw[2][6][16];
    __shared__ int ridx[2][16][3];

    const int s = threadIdx.x / 96;
    const int tp = threadIdx.x - s * 96;
    const int p = blockIdx.x * 2 + s;
    const bool active = p < n;
    const float shift = shiftp[0];

    const int h = tp >> 4;  // 0..5
    const int e = tp & 15;

    int jd = 0;
    if (active) jd = index_1[(size_t)p * 16 + e];

    // ---- rel quantized index: 48 threads/point, one per (e,c)
    if (active && tp < 48) {
        const int c = tp >> 4;
        const float mnc = mn[c];
        float xi = floorf(fmodf(xyz[3 * p + c] - mnc + shift, 4.0f) * 4.0f);
        float xj = floorf(fmodf(xyz[3 * jd + c] - mnc + shift, 4.0f) * 4.0f);
        ridx[s][e][c] = (int)(xi - xj) + 15;
    }

    // ---- gather: k fragment into regs, v fragment into LDS, q row into LDS
    float4 k0, k1, k2, k3;
    k0 = k1 = k2 = k3 = make_float4(0.f, 0.f, 0.f, 0.f);
    if (active) {
        qs[s][tp] = q[(size_t)p * 96 + tp];
        const ushort* row = kv + (size_t)jd * 192;
        uint4 ka = *(const uint4*)(row + h * 16);
        uint4 kb = *(const uint4*)(row + h * 16 + 8);
        uint4 va = *(const uint4*)(row + 96 + h * 16);
        uint4 vb = *(const uint4*)(row + 96 + h * 16 + 8);
        k0 = make_float4(bl(ka.x), bh(ka.x), bl(ka.y), bh(ka.y));
        k1 = make_float4(bl(ka.z), bh(ka.z), bl(ka.w), bh(ka.w));
        k2 = make_float4(bl(kb.x), bh(kb.x), bl(kb.y), bh(kb.y));
        k3 = make_float4(bl(kb.z), bh(kb.z), bl(kb.w), bh(kb.w));
        *(float4*)&vs[s][e][h * 16 + 0]  = make_float4(bl(va.x), bh(va.x), bl(va.y), bh(va.y));
        *(float4*)&vs[s][e][h * 16 + 4]  = make_float4(bl(va.z), bh(va.z), bl(va.w), bh(va.w));
        *(float4*)&vs[s][e][h * 16 + 8]  = make_float4(bl(vb.x), bh(vb.x), bl(vb.y), bh(vb.y));
        *(float4*)&vs[s][e][h * 16 + 12] = make_float4(bl(vb.z), bh(vb.z), bl(vb.w), bh(vb.w));
    }
    __syncthreads();

    // ---- score: qk + bias, then width-16 shuffle softmax
    {
        const float4* q4 = (const float4*)&qs[s][h * 16];
        float4 qa = q4[0], qb = q4[1], qc = q4[2], qd = q4[3];
        float a = dot4(qa, k0) + dot4(qb, k1) + dot4(qc, k2) + dot4(qd, k3);
#pragma unroll
        for (int c = 0; c < 3; c++) {
            int idx = ridx[s][e][c];
            const uint4* tq4 = (const uint4*)(rq + (c * 64 + idx) * 96 + h * 16);
            const uint4* tk4 = (const uint4*)(rk + (c * 64 + idx) * 96 + h * 16);
            uint4 t0 = tq4[0], t1 = tq4[1];
            a += qa.x * bl(t0.x) + qa.y * bh(t0.x) + qa.z * bl(t0.y) + qa.w * bh(t0.y) +
                 qb.x * bl(t0.z) + qb.y * bh(t0.z) + qb.z * bl(t0.w) + qb.w * bh(t0.w) +
                 qc.x * bl(t1.x) + qc.y * bh(t1.x) + qc.z * bl(t1.y) + qc.w * bh(t1.y) +
                 qd.x * bl(t1.z) + qd.y * bh(t1.z) + qd.z * bl(t1.w) + qd.w * bh(t1.w);
            uint4 u0 = tk4[0], u1 = tk4[1];
            a += k0.x * bl(u0.x) + k0.y * bh(u0.x) + k0.z * bl(u0.y) + k0.w * bh(u0.y) +
                 k1.x * bl(u0.z) + k1.y * bh(u0.z) + k1.z * bl(u0.w) + k1.w * bh(u0.w) +
                 k2.x * bl(u1.x) + k2.y * bh(u1.x) + k2.z * bl(u1.y) + k2.w * bh(u1.y) +
                 k3.x * bl(u1.z) + k3.y * bh(u1.z) + k3.z * bl(u1.w) + k3.w * bh(u1.w);
        }
        // width-16 softmax across e lanes (tp ≡ lane mod 16 holds for 192-blocks)
        float m = a;
#pragma unroll
        for (int off = 8; off >= 1; off >>= 1) m = fmaxf(m, __shfl_xor(m, off, 16));
        float ex = __expf(a - m);
        float sum = ex;
#pragma unroll
        for (int off = 8; off >= 1; off >>= 1) sum += __shfl_xor(sum, off, 16);
        if (active) smw[s][h][e] = ex / sum;
    }
    __syncthreads();

    // ---- output: thread owns (h,d)=tp, emit bf16 x
    {
        float x = 0.f;
#pragma unroll
        for (int ee = 0; ee < 16; ee++) {
            float wgt = smw[s][h][ee];
            int i0 = ridx[s][ee][0], i1 = ridx[s][ee][1], i2 = ridx[s][ee][2];
            float add = bs(rv[i0 * 96 + tp]) + bs(rv[(64 + i1) * 96 + tp]) +
                        bs(rv[(128 + i2) * 96 + tp]);
            x += wgt * (vs[s][ee][tp] + add);
        }
        if (active) xout[(size_t)p * 96 + tp] = f2bf(x);
    }
}

// ---------------------------------------------------------------- launch
extern "C" void kernel_launch(void* const* d_in, const int* in_sizes, int n_in,
                              void* d_out, int out_size, void* d_ws, size_t ws_size,
                              hipStream_t stream) {
    const float* feats   = (const float*)d_in[0];
    const float* xyz     = (const float*)d_in[1];
    const int*   index_1 = (const int*)d_in[5];
    const float* shiftp  = (const float*)d_in[6];
    const float* W_qkv   = (const float*)d_in[7];
    const float* b_qkv   = (const float*)d_in[8];
    const float* table_q = (const float*)d_in[9];
    const float* table_k = (const float*)d_in[10];
    const float* table_v = (const float*)d_in[11];
    const float* W_proj  = (const float*)d_in[12];
    const float* b_proj  = (const float*)d_in[13];
    float* out = (float*)d_out;

    const int n = in_sizes[0] / 96;  // 50000

    float* w = (float*)d_ws;
    float*  mn       = w;                                  // 16 floats
    float*  qbuf     = w + 16;                             // n*96 fp32
    ushort* kvbuf    = (ushort*)(qbuf + (size_t)n * 96);   // n*192 bf16
    ushort* feats_bf = kvbuf + (size_t)n * 192;            // n*96 bf16
    ushort* xbuf_bf  = feats_bf;  // alias: feats consumed by qkv GEMM before attn writes x
    ushort* wtqkv    = feats_bf + (size_t)n * 96;          // 27648
    ushort* wtproj   = wtqkv + 27648;                      // 9216
    ushort* rq       = wtproj + 9216;                      // 18432 each
    ushort* rk       = rq + 18432;
    ushort* rv       = rk + 18432;

    const int GB = (n / 16 + 3) / 4;  // wave-jobs of 16 rows, 4 waves/block

    prep_kernel<<<(n * 24 + 255) / 256, 256, 0, stream>>>(
        feats, W_qkv, W_proj, table_q, table_k, table_v, feats_bf, wtqkv, wtproj,
        rq, rk, rv, mn, n);
    min_reduce_kernel<<<256, 256, 0, stream>>>(xyz, n, mn);
    mfma_gemm_kernel<<<dim3(GB, 3), 256, 0, stream>>>(feats_bf, wtqkv, b_qkv, qbuf,
                                                      kvbuf, 0.25f, n);
    attn_kernel<<<(n + 1) / 2, 192, 0, stream>>>(qbuf, kvbuf, xyz, index_1, rq, rk,
                                                 rv, mn, shiftp, xbuf_bf, n);
    mfma_gemm_kernel<<<dim3(GB, 1), 256, 0, stream>>>(xbuf_bf, wtproj, b_proj, out,
                                                      kvbuf, 1.0f, n);
}

// Round 6
// 276.722 us; speedup vs baseline: 1.8367x; 1.0763x over previous
//
#include <hip/hip_runtime.h>
#include <math.h>

#define FLT_BIG 3.402823466e38f
typedef unsigned int uint;
typedef unsigned short ushort;
typedef __attribute__((ext_vector_type(8))) short short8;   // 8 bf16 (4 VGPRs)
typedef __attribute__((ext_vector_type(4))) float floatx4;  // MFMA C/D frag

__device__ inline float bl(uint u) { return __uint_as_float(u << 16); }
__device__ inline float bh(uint u) { return __uint_as_float(u & 0xffff0000u); }
__device__ inline ushort f2bf(float f) {  // RNE
    uint u = __float_as_uint(f);
    return (ushort)((u + 0x7fffu + ((u >> 16) & 1u)) >> 16);
}
__device__ inline float dot4(float4 a, float4 b) {
    return a.x * b.x + a.y * b.y + a.z * b.z + a.w * b.w;
}

// ---------------------------------------------------------------- min(xyz)
__global__ void min_reduce_kernel(const float* __restrict__ xyz, int n, float* mn) {
    float m0 = FLT_BIG, m1 = FLT_BIG, m2 = FLT_BIG;
    for (int i = blockIdx.x * blockDim.x + threadIdx.x; i < n; i += gridDim.x * blockDim.x) {
        m0 = fminf(m0, xyz[3 * i + 0]);
        m1 = fminf(m1, xyz[3 * i + 1]);
        m2 = fminf(m2, xyz[3 * i + 2]);
    }
#pragma unroll
    for (int off = 32; off > 0; off >>= 1) {
        m0 = fminf(m0, __shfl_down(m0, off));
        m1 = fminf(m1, __shfl_down(m1, off));
        m2 = fminf(m2, __shfl_down(m2, off));
    }
    if ((threadIdx.x & 63) == 0) {
        // xyz >= 0 so float bits are monotone under signed int compare
        atomicMin((int*)&mn[0], __float_as_int(m0));
        atomicMin((int*)&mn[1], __float_as_int(m1));
        atomicMin((int*)&mn[2], __float_as_int(m2));
    }
}

// ---------------------------------------------------------------- prep (small)
// mn init; tables [idx][hd][c] -> [c][idx][hd] bf16; W transposes -> bf16.
// grid 108 x 256 covers max task count (27648).
__global__ void prep_kernel(const float* __restrict__ W_qkv,
                            const float* __restrict__ W_proj,
                            const float* __restrict__ tq, const float* __restrict__ tk,
                            const float* __restrict__ tv,
                            ushort* __restrict__ wtqkv, ushort* __restrict__ wtproj,
                            ushort* __restrict__ rq, ushort* __restrict__ rk,
                            ushort* __restrict__ rv, float* mn) {
    int tid = blockIdx.x * 256 + threadIdx.x;
    if (tid < 3) mn[tid] = FLT_BIG;
    if (tid < 18432) {  // tables: 3*64*96
        int c = tid / 6144, rem = tid - c * 6144;
        int idx = rem / 96, hd = rem - idx * 96;
        int src = (idx * 96 + hd) * 3 + c;
        rq[tid] = f2bf(tq[src]);
        rk[tid] = f2bf(tk[src]);
        rv[tid] = f2bf(tv[src]);
    }
    if (tid < 27648) {  // WT_qkv[j][d] = W_qkv[d][j], j over 288
        int j = tid / 96, d = tid - j * 96;
        wtqkv[tid] = f2bf(W_qkv[d * 288 + j]);
    }
    if (tid < 9216) {  // WT_proj[j][d] = W_proj[d][j]
        int j = tid / 96, d = tid - j * 96;
        wtproj[tid] = f2bf(W_proj[d * 96 + j]);
    }
}

// ---------------------------------------------------------------- QKV MFMA GEMM
// feats fp32 (n x 96) @ WT^T + bias -> q bf16 (x0.25) | kv bf16 interleaved.
// Wave job: 32 rows x 96 cols, K=96. Epilogue: per-wave LDS repack (pitch 112
// ushorts -> disjoint bank groups for the 4 q-rows), uint4 coalesced stores.
// Verified frag layouts (R5 / m89/m91): A[m=lane&15][k=q*8+j],
// B[k=q*8+j][col=lane&15], D[row=q*4+r][col=lane&15].
__global__ __launch_bounds__(256) void qkv_mfma_kernel(
    const float* __restrict__ A, const ushort* __restrict__ WT,
    const float* __restrict__ bias, uint4* __restrict__ qout4,
    uint4* __restrict__ kvout4, int n) {
    __shared__ ushort lds[4][32 * 112];
    const int wave = threadIdx.x >> 6, lane = threadIdx.x & 63;
    const int ch = blockIdx.y;
    const int m = lane & 15, q = lane >> 4;
    const int row0 = blockIdx.x * 128 + wave * 32;
    if (row0 >= n) return;

    const ushort* wbase = WT + ((size_t)ch * 96 + m) * 96 + q * 8;
    int r0 = row0 + m;      if (r0 > n - 1) r0 = n - 1;
    int r1 = row0 + 16 + m; if (r1 > n - 1) r1 = n - 1;
    const float4* A4 = (const float4*)A;

    floatx4 acc[2][6];
#pragma unroll
    for (int g = 0; g < 2; g++)
#pragma unroll
        for (int ct = 0; ct < 6; ct++) acc[g][ct] = (floatx4){0.f, 0.f, 0.f, 0.f};

#pragma unroll
    for (int kk4 = 0; kk4 < 24; kk4 += 8) {  // k offset in float4 units
        float4 fa = A4[(size_t)r0 * 24 + kk4 + q * 2];
        float4 fb = A4[(size_t)r0 * 24 + kk4 + q * 2 + 1];
        float4 ga = A4[(size_t)r1 * 24 + kk4 + q * 2];
        float4 gb = A4[(size_t)r1 * 24 + kk4 + q * 2 + 1];
        short8 a0, a1;
        a0[0] = f2bf(fa.x); a0[1] = f2bf(fa.y); a0[2] = f2bf(fa.z); a0[3] = f2bf(fa.w);
        a0[4] = f2bf(fb.x); a0[5] = f2bf(fb.y); a0[6] = f2bf(fb.z); a0[7] = f2bf(fb.w);
        a1[0] = f2bf(ga.x); a1[1] = f2bf(ga.y); a1[2] = f2bf(ga.z); a1[3] = f2bf(ga.w);
        a1[4] = f2bf(gb.x); a1[5] = f2bf(gb.y); a1[6] = f2bf(gb.z); a1[7] = f2bf(gb.w);
#pragma unroll
        for (int ct = 0; ct < 6; ct++) {
            short8 b = *(const short8*)(wbase + ct * 16 * 96 + kk4 * 4);
            acc[0][ct] = __builtin_amdgcn_mfma_f32_16x16x32_bf16(a0, b, acc[0][ct], 0, 0, 0);
            acc[1][ct] = __builtin_amdgcn_mfma_f32_16x16x32_bf16(a1, b, acc[1][ct], 0, 0, 0);
        }
    }

    ushort* L = lds[wave];
    const float sc = (ch == 0) ? 0.25f : 1.0f;
#pragma unroll
    for (int g = 0; g < 2; g++)
#pragma unroll
        for (int ct = 0; ct < 6; ct++) {
            float bv = bias[ch * 96 + ct * 16 + m];
#pragma unroll
            for (int r = 0; r < 4; r++) {
                int rowl = g * 16 + q * 4 + r;
                L[rowl * 112 + ct * 16 + m] = f2bf((acc[g][ct][r] + bv) * sc);
            }
        }
    // wave-internal LDS RAW: compiler inserts lgkmcnt wait, no barrier needed
    const int strideU4 = (ch == 0) ? 12 : 24;
    const int offU4 = (ch == 2) ? 12 : 0;
    uint4* dst = (ch == 0) ? qout4 : kvout4;
#pragma unroll
    for (int i = 0; i < 6; i++) {
        int idx = i * 64 + lane;  // 0..383 over 32 rows x 12 uint4
        int rowl = idx / 12, u4 = idx - rowl * 12;
        int grow = row0 + rowl;
        if (grow < n) {
            uint4 val = *(const uint4*)(L + rowl * 112 + u4 * 8);
            dst[(size_t)grow * strideU4 + offU4 + u4] = val;
        }
    }
}

// ---------------------------------------------------------------- proj MFMA GEMM
// x bf16 (n x 96) @ WT_proj^T + bias -> out fp32.
__global__ __launch_bounds__(256) void proj_mfma_kernel(
    const ushort* __restrict__ A, const ushort* __restrict__ WT,
    const float* __restrict__ bias, float* __restrict__ out, int n) {
    const int wave = threadIdx.x >> 6, lane = threadIdx.x & 63;
    const int m = lane & 15, q = lane >> 4;
    const int row0 = blockIdx.x * 128 + wave * 32;
    if (row0 >= n) return;

    const ushort* wbase = WT + (size_t)m * 96 + q * 8;
    int r0 = row0 + m;      if (r0 > n - 1) r0 = n - 1;
    int r1 = row0 + 16 + m; if (r1 > n - 1) r1 = n - 1;

    floatx4 acc[2][6];
#pragma unroll
    for (int g = 0; g < 2; g++)
#pragma unroll
        for (int ct = 0; ct < 6; ct++) acc[g][ct] = (floatx4){0.f, 0.f, 0.f, 0.f};

#pragma unroll
    for (int kk = 0; kk < 96; kk += 32) {
        short8 a0 = *(const short8*)(A + (size_t)r0 * 96 + q * 8 + kk);
        short8 a1 = *(const short8*)(A + (size_t)r1 * 96 + q * 8 + kk);
#pragma unroll
        for (int ct = 0; ct < 6; ct++) {
            short8 b = *(const short8*)(wbase + ct * 16 * 96 + kk);
            acc[0][ct] = __builtin_amdgcn_mfma_f32_16x16x32_bf16(a0, b, acc[0][ct], 0, 0, 0);
            acc[1][ct] = __builtin_amdgcn_mfma_f32_16x16x32_bf16(a1, b, acc[1][ct], 0, 0, 0);
        }
    }

#pragma unroll
    for (int g = 0; g < 2; g++)
#pragma unroll
        for (int ct = 0; ct < 6; ct++) {
            int col = ct * 16 + m;
            float bv = bias[col];
#pragma unroll
            for (int r = 0; r < 4; r++) {
                int row = row0 + g * 16 + q * 4 + r;
                if (row < n) out[(size_t)row * 96 + col] = acc[g][ct][r] + bv;
            }
        }
}

// ---------------------------------------------------------------- fused attention
// q bf16, kv bf16 (k[96]||v[96] 384B rows). Thread (h,e): k fragment straight
// into regs; v fragment -> LDS; table-v bias folded into LDS v-tile with
// vectorized uint4 loads; output loop is pure LDS-FMA. x out bf16.
__global__ __launch_bounds__(192) void attn_kernel(
    const ushort* __restrict__ qbf, const ushort* __restrict__ kv,
    const float* __restrict__ xyz, const int* __restrict__ index_1,
    const ushort* __restrict__ rq, const ushort* __restrict__ rk,
    const ushort* __restrict__ rv, const float* __restrict__ mn,
    const float* __restrict__ shiftp, ushort* xout, int n) {
    __shared__ float qs[2][96];
    __shared__ float vs[2][16][104];  // pitch 104 floats (16B-aligned rows)
    __shared__ float smw[2][6][16];
    __shared__ int ridx[2][16][3];

    const int s = threadIdx.x / 96;
    const int tp = threadIdx.x - s * 96;
    const int p = blockIdx.x * 2 + s;
    const bool active = p < n;
    const float shift = shiftp[0];

    const int h = tp >> 4;  // 0..5
    const int e = tp & 15;

    int jd = 0;
    if (active) jd = index_1[(size_t)p * 16 + e];

    // ---- rel quantized index (48 thr/point) + q row unpack (48 thr/point)
    if (active && tp < 48) {
        const int c = tp >> 4;
        const float mnc = mn[c];
        float xi = floorf(fmodf(xyz[3 * p + c] - mnc + shift, 4.0f) * 4.0f);
        float xj = floorf(fmodf(xyz[3 * jd + c] - mnc + shift, 4.0f) * 4.0f);
        ridx[s][e][c] = (int)(xi - xj) + 15;
        uint qu = *(const uint*)(qbf + (size_t)p * 96 + tp * 2);
        qs[s][tp * 2] = bl(qu);
        qs[s][tp * 2 + 1] = bh(qu);
    }

    // ---- gather: k fragment into regs, v fragment into LDS
    float4 k0, k1, k2, k3;
    k0 = k1 = k2 = k3 = make_float4(0.f, 0.f, 0.f, 0.f);
    if (active) {
        const ushort* row = kv + (size_t)jd * 192;
        uint4 ka = *(const uint4*)(row + h * 16);
        uint4 kb = *(const uint4*)(row + h * 16 + 8);
        uint4 va = *(const uint4*)(row + 96 + h * 16);
        uint4 vb = *(const uint4*)(row + 96 + h * 16 + 8);
        k0 = make_float4(bl(ka.x), bh(ka.x), bl(ka.y), bh(ka.y));
        k1 = make_float4(bl(ka.z), bh(ka.z), bl(ka.w), bh(ka.w));
        k2 = make_float4(bl(kb.x), bh(kb.x), bl(kb.y), bh(kb.y));
        k3 = make_float4(bl(kb.z), bh(kb.z), bl(kb.w), bh(kb.w));
        *(float4*)&vs[s][e][h * 16 + 0]  = make_float4(bl(va.x), bh(va.x), bl(va.y), bh(va.y));
        *(float4*)&vs[s][e][h * 16 + 4]  = make_float4(bl(va.z), bh(va.z), bl(va.w), bh(va.w));
        *(float4*)&vs[s][e][h * 16 + 8]  = make_float4(bl(vb.x), bh(vb.x), bl(vb.y), bh(vb.y));
        *(float4*)&vs[s][e][h * 16 + 12] = make_float4(bl(vb.z), bh(vb.z), bl(vb.w), bh(vb.w));
    }
    __syncthreads();

    // ---- fold table-v bias into vs: 192 tasks (e2, 8-col chunk), 2 per thread
    if (active) {
#pragma unroll
        for (int it = 0; it < 2; it++) {
            int t2 = tp + 96 * it;
            int e2 = t2 / 12, c8 = t2 - e2 * 12;
            int i0 = ridx[s][e2][0], i1 = ridx[s][e2][1], i2 = ridx[s][e2][2];
            uint4 u0 = *(const uint4*)(rv + i0 * 96 + c8 * 8);
            uint4 u1 = *(const uint4*)(rv + (64 + i1) * 96 + c8 * 8);
            uint4 u2 = *(const uint4*)(rv + (128 + i2) * 96 + c8 * 8);
            float4* vp = (float4*)&vs[s][e2][c8 * 8];
            float4 a0 = vp[0], a1 = vp[1];
            a0.x += bl(u0.x) + bl(u1.x) + bl(u2.x);
            a0.y += bh(u0.x) + bh(u1.x) + bh(u2.x);
            a0.z += bl(u0.y) + bl(u1.y) + bl(u2.y);
            a0.w += bh(u0.y) + bh(u1.y) + bh(u2.y);
            a1.x += bl(u0.z) + bl(u1.z) + bl(u2.z);
            a1.y += bh(u0.z) + bh(u1.z) + bh(u2.z);
            a1.z += bl(u0.w) + bl(u1.w) + bl(u2.w);
            a1.w += bh(u0.w) + bh(u1.w) + bh(u2.w);
            vp[0] = a0; vp[1] = a1;
        }
    }

    // ---- score: qk + bias tables, then width-16 shuffle softmax
    {
        const float4* q4 = (const float4*)&qs[s][h * 16];
        float4 qa = q4[0], qb = q4[1], qc = q4[2], qd = q4[3];
        float a = dot4(qa, k0) + dot4(qb, k1) + dot4(qc, k2) + dot4(qd, k3);
#pragma unroll
        for (int c = 0; c < 3; c++) {
            int idx = ridx[s][e][c];
            const uint4* tq4 = (const uint4*)(rq + (c * 64 + idx) * 96 + h * 16);
            const uint4* tk4 = (const uint4*)(rk + (c * 64 + idx) * 96 + h * 16);
            uint4 t0 = tq4[0], t1 = tq4[1];
            a += qa.x * bl(t0.x) + qa.y * bh(t0.x) + qa.z * bl(t0.y) + qa.w * bh(t0.y) +
                 qb.x * bl(t0.z) + qb.y * bh(t0.z) + qb.z * bl(t0.w) + qb.w * bh(t0.w) +
                 qc.x * bl(t1.x) + qc.y * bh(t1.x) + qc.z * bl(t1.y) + qc.w * bh(t1.y) +
                 qd.x * bl(t1.z) + qd.y * bh(t1.z) + qd.z * bl(t1.w) + qd.w * bh(t1.w);
            uint4 u0 = tk4[0], u1 = tk4[1];
            a += k0.x * bl(u0.x) + k0.y * bh(u0.x) + k0.z * bl(u0.y) + k0.w * bh(u0.y) +
                 k1.x * bl(u0.z) + k1.y * bh(u0.z) + k1.z * bl(u0.w) + k1.w * bh(u0.w) +
                 k2.x * bl(u1.x) + k2.y * bh(u1.x) + k2.z * bl(u1.y) + k2.w * bh(u1.y) +
                 k3.x * bl(u1.z) + k3.y * bh(u1.z) + k3.z * bl(u1.w) + k3.w * bh(u1.w);
        }
        float m = a;
#pragma unroll
        for (int off = 8; off >= 1; off >>= 1) m = fmaxf(m, __shfl_xor(m, off, 16));
        float ex = __expf(a - m);
        float sum = ex;
#pragma unroll
        for (int off = 8; off >= 1; off >>= 1) sum += __shfl_xor(sum, off, 16);
        if (active) smw[s][h][e] = ex / sum;
    }
    __syncthreads();

    // ---- output: pure LDS-FMA, emit bf16 x
    {
        float x = 0.f;
#pragma unroll
        for (int ee = 0; ee < 16; ee++) x += smw[s][h][ee] * vs[s][ee][tp];
        if (active) xout[(size_t)p * 96 + tp] = f2bf(x);
    }
}

// ---------------------------------------------------------------- launch
extern "C" void kernel_launch(void* const* d_in, const int* in_sizes, int n_in,
                              void* d_out, int out_size, void* d_ws, size_t ws_size,
                              hipStream_t stream) {
    const float* feats   = (const float*)d_in[0];
    const float* xyz     = (const float*)d_in[1];
    const int*   index_1 = (const int*)d_in[5];
    const float* shiftp  = (const float*)d_in[6];
    const float* W_qkv   = (const float*)d_in[7];
    const float* b_qkv   = (const float*)d_in[8];
    const float* table_q = (const float*)d_in[9];
    const float* table_k = (const float*)d_in[10];
    const float* table_v = (const float*)d_in[11];
    const float* W_proj  = (const float*)d_in[12];
    const float* b_proj  = (const float*)d_in[13];
    float* out = (float*)d_out;

    const int n = in_sizes[0] / 96;  // 50000

    float* w = (float*)d_ws;
    float*  mn     = w;                         // 16 floats
    ushort* qbf    = (ushort*)(w + 16);         // n*96 bf16
    ushort* kvbuf  = qbf + (size_t)n * 96;      // n*192 bf16
    ushort* xbuf   = kvbuf + (size_t)n * 192;   // n*96 bf16
    ushort* wtqkv  = xbuf + (size_t)n * 96;     // 27648
    ushort* wtproj = wtqkv + 27648;             // 9216
    ushort* rq     = wtproj + 9216;             // 18432 each
    ushort* rk     = rq + 18432;
    ushort* rv     = rk + 18432;

    const int GB = (n + 127) / 128;

    prep_kernel<<<108, 256, 0, stream>>>(W_qkv, W_proj, table_q, table_k, table_v,
                                         wtqkv, wtproj, rq, rk, rv, mn);
    min_reduce_kernel<<<256, 256, 0, stream>>>(xyz, n, mn);
    qkv_mfma_kernel<<<dim3(GB, 3), 256, 0, stream>>>(feats, wtqkv, b_qkv,
                                                     (uint4*)qbf, (uint4*)kvbuf, n);
    attn_kernel<<<(n + 1) / 2, 192, 0, stream>>>(qbf, kvbuf, xyz, index_1, rq, rk,
                                                 rv, mn, shiftp, xbuf, n);
    proj_mfma_kernel<<<GB, 256, 0, stream>>>(xbuf, wtproj, b_proj, out, n);
}